// Round 10
// baseline (174.960 us; speedup 1.0000x reference)
//
#include <hip/hip_runtime.h>

#define T_LEN 120000
#define LBLK 160          // scan block length (divides 40000)
#define PBLK 750          // scan blocks
#define SEG_LEN 25        // blocks per scan segment
#define NSEG 30           // segments
#define BATCH 4
#define KV_LO 250         // first valid scan block (t = 40000)
#define NKV 250           // valid scan blocks
#define TV0 40000         // first valid t
#define NTV 40000         // valid t count
#define DENOM 20480000.0  // 2 * 4 * 64 * 40000 (each |diff| counted twice)
#define NSLOT 128         // atomic accumulation slots

typedef _Float16 half8 __attribute__((ext_vector_type(8)));
typedef float f32x4 __attribute__((ext_vector_type(4)));

__device__ __forceinline__ float fast_tanh(float x) {
  float e = __expf(2.0f * x);
  return 1.0f - 2.0f / (e + 1.0f);
}

// Harness may store the reference's float64 arrays as f64 or f32. Detect via
// a2[0] = r^2 in (0.9,1.0) (f32-reinterpret fails the window). Data-stable.
__device__ __forceinline__ bool coeffs_are_f64(const void* a2p) {
  double probe = *(const double*)a2p;
  return probe > 0.9 && probe < 1.0;
}
__device__ __forceinline__ double coeff_d(const void* p, bool f64, int ch) {
  return f64 ? ((const double*)p)[ch] : (double)((const float*)p)[ch];
}

// A^e for A = [[-a1,-a2],[1,0]] by repeated squaring (f64)
__device__ __forceinline__ void mat_pow(double A1, double A2, int e,
                                        double& r00, double& r01,
                                        double& r10, double& r11) {
  double m00 = -A1, m01 = -A2, m10 = 1.0, m11 = 0.0;
  r00 = 1.0; r01 = 0.0; r10 = 0.0; r11 = 1.0;
  while (e) {
    if (e & 1) {
      double t00 = r00 * m00 + r01 * m10, t01 = r00 * m01 + r01 * m11;
      double t10 = r10 * m00 + r11 * m10, t11 = r10 * m01 + r11 * m11;
      r00 = t00; r01 = t01; r10 = t10; r11 = t11;
    }
    e >>= 1;
    if (e) {
      double t00 = m00 * m00 + m01 * m10, t01 = m00 * m01 + m01 * m11;
      double t10 = m10 * m00 + m11 * m10, t11 = m10 * m01 + m11 * m11;
      m00 = t00; m01 = t01; m10 = t10; m11 = t11;
    }
  }
}

// Pass 1: per (row, block) forced response with zero initial state, f32.
// rows r = i*8 + d*4 + b. Stored as f32 (computed in f32 -> no loss).
// Block (0,0) also zeroes the wsum slots.
__global__ __launch_bounds__(64) void pass1(
    const float* __restrict__ pred, const float* __restrict__ tgt,
    const void* a1p, const void* a2p, const void* b0p,
    float2* __restrict__ fbuf, double* __restrict__ wsum)
{
  int k = blockIdx.x, r = blockIdx.y;
  if (k == 0 && r == 0 && threadIdx.x == 0) {
    #pragma unroll
    for (int q = 0; q < 2; ++q) ((double*)wsum)[0] = 0.0; // placate compiler
  }
  if (k == 0 && r == 1 && threadIdx.x < 64) {
    wsum[threadIdx.x] = 0.0; wsum[64 + threadIdx.x] = 0.0;
  }
  int i = r >> 3, d = (r >> 2) & 1, b = r & 3;
  const float* sig = (i ? tgt : pred) + b * T_LEN;
  __shared__ float xs[LBLK];
  int base = k * LBLK;
  for (int j = threadIdx.x; j < LBLK; j += 64)
    xs[j] = d ? sig[T_LEN - 1 - (base + j)] : sig[base + j];
  __syncthreads();
  int ch = threadIdx.x;
  bool f64 = coeffs_are_f64(a2p);
  float A1 = (float)coeff_d(a1p, f64, ch);
  float A2 = (float)coeff_d(a2p, f64, ch);
  float B0 = (float)coeff_d(b0p, f64, ch);
  float y1 = 0.0f, y2 = 0.0f;
  for (int j = 0; j < LBLK; ++j) {
    float y = fmaf(-A1, y1, fmaf(-A2, y2, B0 * xs[j]));
    y2 = y1; y1 = y;
  }
  fbuf[(size_t)k * 1024 + r * 64 + ch] = make_float2(y1, y2);
}

// Pass 2a: per-segment aggregate (forced response of 25 blocks, zero init), f64.
__global__ __launch_bounds__(64) void pass2a(
    const void* a1p, const void* a2p,
    const float2* __restrict__ fbuf, double* __restrict__ sbuf)
{
  int seg = blockIdx.x >> 4;
  int s = ((blockIdx.x & 15) << 6) + threadIdx.x;
  int ch = s & 63;
  bool f64 = coeffs_are_f64(a2p);
  double r00, r01, r10, r11;
  mat_pow(coeff_d(a1p, f64, ch), coeff_d(a2p, f64, ch), LBLK, r00, r01, r10, r11);
  double y1 = 0.0, y2 = 0.0;
  #pragma unroll 1
  for (int jj = 0; jj < SEG_LEN / 5; ++jj) {
    size_t kb = (size_t)(seg * SEG_LEN + jj * 5) * 1024 + s;
    float2 f0 = fbuf[kb], f1 = fbuf[kb + 1024], f2 = fbuf[kb + 2048],
           f3 = fbuf[kb + 3072], f4 = fbuf[kb + 4096];
    double n1, n2;
    n1 = r00*y1 + r01*y2 + (double)f0.x; n2 = r10*y1 + r11*y2 + (double)f0.y; y1=n1; y2=n2;
    n1 = r00*y1 + r01*y2 + (double)f1.x; n2 = r10*y1 + r11*y2 + (double)f1.y; y1=n1; y2=n2;
    n1 = r00*y1 + r01*y2 + (double)f2.x; n2 = r10*y1 + r11*y2 + (double)f2.y; y1=n1; y2=n2;
    n1 = r00*y1 + r01*y2 + (double)f3.x; n2 = r10*y1 + r11*y2 + (double)f3.y; y1=n1; y2=n2;
    n1 = r00*y1 + r01*y2 + (double)f4.x; n2 = r10*y1 + r11*y2 + (double)f4.y; y1=n1; y2=n2;
  }
  ((double2*)sbuf)[(size_t)seg * 1024 + s] = make_double2(y1, y2);
}

// Pass 2b: serial scan over the 30 segment aggregates -> segment-start states.
__global__ __launch_bounds__(256) void pass2b(
    const void* a1p, const void* a2p,
    const double* __restrict__ sbuf, double* __restrict__ tbuf)
{
  int s = blockIdx.x * 256 + threadIdx.x;
  int ch = s & 63;
  bool f64 = coeffs_are_f64(a2p);
  double r00, r01, r10, r11;
  mat_pow(coeff_d(a1p, f64, ch), coeff_d(a2p, f64, ch), LBLK * SEG_LEN,
          r00, r01, r10, r11);
  const double2* sb = (const double2*)sbuf;
  double2* tb = (double2*)tbuf;
  double y1 = 0.0, y2 = 0.0;
  #pragma unroll 1
  for (int bb = 0; bb < NSEG; bb += 15) {
    double2 f[15];
    #pragma unroll
    for (int q = 0; q < 15; ++q) f[q] = sb[(size_t)(bb + q) * 1024 + s];
    #pragma unroll
    for (int q = 0; q < 15; ++q) {
      tb[(size_t)(bb + q) * 1024 + s] = make_double2(y1, y2);
      double n1 = r00 * y1 + r01 * y2 + f[q].x;
      double n2 = r10 * y1 + r11 * y2 + f[q].y;
      y1 = n1; y2 = n2;
    }
  }
}

// Pass 2c: per (scan block k in [250,500), row r): compose <=24 block
// aggregates from tbuf[seg], then walk 160 exact f64 sample-steps, emitting
// f16 y DIRECTLY into ybuf[b][t-40000][i][128] (fwd ch 0-63, bwd ch 64-127).
// Both directions are forward walks of their own scan signal; scan pos p of
// the bwd signal lands at output t = T_LEN-1-p (block-aligned since 750*160).
__global__ __launch_bounds__(64) void pass2c(
    const float* __restrict__ pred, const float* __restrict__ tgt,
    const void* a1p, const void* a2p, const void* b0p,
    const float2* __restrict__ fbuf, const double* __restrict__ tbuf,
    _Float16* __restrict__ ybuf)
{
  int k = KV_LO + blockIdx.x;
  int r = blockIdx.y;
  int ch = threadIdx.x;
  int i = r >> 3, d = (r >> 2) & 1, b = r & 3;
  int s = r * 64 + ch;
  bool f64 = coeffs_are_f64(a2p);
  double A1 = coeff_d(a1p, f64, ch), A2 = coeff_d(a2p, f64, ch);
  double B0 = coeff_d(b0p, f64, ch);
  double r00, r01, r10, r11;
  mat_pow(A1, A2, LBLK, r00, r01, r10, r11);

  int seg = k / SEG_LEN, j0 = k - seg * SEG_LEN;   // j0 in [0,24]
  double2 v0 = ((const double2*)tbuf)[(size_t)seg * 1024 + s];
  double y1 = v0.x, y2 = v0.y;
  const float2* fb = fbuf + (size_t)(seg * SEG_LEN) * 1024 + s;
  #pragma unroll 1
  for (int bb = 0; bb < 24; bb += 8) {
    float2 f[8];
    #pragma unroll
    for (int q = 0; q < 8; ++q) f[q] = fb[(size_t)(bb + q) * 1024];
    #pragma unroll
    for (int q = 0; q < 8; ++q) {
      if (bb + q < j0) {    // uniform predicate
        double n1 = r00 * y1 + r01 * y2 + (double)f[q].x;
        double n2 = r10 * y1 + r11 * y2 + (double)f[q].y;
        y1 = n1; y2 = n2;
      }
    }
  }

  // exact f64 sample walk; x index == output t index for both directions
  const float* sig = (i ? tgt : pred) + b * T_LEN;
  int p0 = k * LBLK;
  size_t rowbase = (size_t)b * NTV;
  #pragma unroll 4
  for (int idx = 0; idx < LBLK; ++idx) {
    int p = p0 + idx;
    int q = d ? (T_LEN - 1 - p) : p;     // signal index AND output t
    double x = (double)sig[q];
    double y = fma(-A1, y1, fma(-A2, y2, B0 * x));
    ybuf[((rowbase + (q - TV0)) * 2 + i) * 128 + 64 * d + ch] = (_Float16)y;
    y2 = y1; y1 = y;
  }
}

// Pass 3: pure streaming GEMM + tanh + |p-t| reduce. No LDS tiles, no
// recurrence, no barriers. wg = (160-t slab, b); wave gu handles 5 16-col
// B-fragments loaded straight from ybuf; W-frags register-resident.
// Col n = 2*t_local + i -> pred/tgt pairing via shfl_xor(lane,1).
__global__ __launch_bounds__(256, 4) void pass3(
    const float* __restrict__ W, const _Float16* __restrict__ ybuf,
    double* __restrict__ wsum)
{
  int bx = blockIdx.x;            // 160-t slab
  int b = blockIdx.y;
  int tid = threadIdx.x;
  __shared__ float red[4];

  int g = tid >> 6, lane = tid & 63;
  int gu = __builtin_amdgcn_readfirstlane(g);
  int lm = lane & 15, quad = lane >> 4;

  // W fragments f32 -> f16 in registers
  half8 wf[4][4];
  #pragma unroll
  for (int m0 = 0; m0 < 4; ++m0) {
    #pragma unroll
    for (int q = 0; q < 4; ++q) {
      const float* wp = W + (m0 * 16 + lm) * 128 + q * 32 + quad * 8;
      float4 wa = *(const float4*)wp, wb = *(const float4*)(wp + 4);
      half8 h;
      h[0] = (_Float16)wa.x; h[1] = (_Float16)wa.y;
      h[2] = (_Float16)wa.z; h[3] = (_Float16)wa.w;
      h[4] = (_Float16)wb.x; h[5] = (_Float16)wb.y;
      h[6] = (_Float16)wb.z; h[7] = (_Float16)wb.w;
      wf[m0][q] = h;
    }
  }

  // this wg's 320 cols (160 t x 2 inputs)
  const _Float16* yb = ybuf + ((size_t)b * NTV + (size_t)bx * 160) * 256;

  float loss = 0.0f;
  #pragma unroll
  for (int tile = 0; tile < 5; ++tile) {
    int n0 = tile * 64 + gu * 16;          // wave's 16-col tile
    const _Float16* col = yb + (size_t)(n0 + lm) * 128 + quad * 8;
    half8 bf0 = *(const half8*)(col);
    half8 bf1 = *(const half8*)(col + 32);
    half8 bf2 = *(const half8*)(col + 64);
    half8 bf3 = *(const half8*)(col + 96);
    #pragma unroll
    for (int m0 = 0; m0 < 4; ++m0) {
      f32x4 c = {0.f, 0.f, 0.f, 0.f};
      c = __builtin_amdgcn_mfma_f32_16x16x32_f16(wf[m0][0], bf0, c, 0, 0, 0);
      c = __builtin_amdgcn_mfma_f32_16x16x32_f16(wf[m0][1], bf1, c, 0, 0, 0);
      c = __builtin_amdgcn_mfma_f32_16x16x32_f16(wf[m0][2], bf2, c, 0, 0, 0);
      c = __builtin_amdgcn_mfma_f32_16x16x32_f16(wf[m0][3], bf3, c, 0, 0, 0);
      #pragma unroll
      for (int rr = 0; rr < 4; ++rr) {
        float vv = fast_tanh(c[rr]);
        float p = __shfl_xor(vv, 1);   // partner col = other input, same t
        loss += fabsf(vv - p);
      }
    }
  }

  // block reduction -> one double atomic per wg, spread over 128 slots
  #pragma unroll
  for (int off = 32; off > 0; off >>= 1) loss += __shfl_down(loss, off);
  if ((tid & 63) == 0) red[tid >> 6] = loss;
  __syncthreads();
  if (tid == 0) {
    int slot = (blockIdx.x * 4 + blockIdx.y) & (NSLOT - 1);
    atomicAdd(&wsum[slot], (double)(red[0] + red[1] + red[2] + red[3]));
  }
}

__global__ __launch_bounds__(128) void finalize(
    const double* __restrict__ wsum, float* __restrict__ out) {
  __shared__ double part[2];
  int tid = threadIdx.x;
  double v = wsum[tid];
  #pragma unroll
  for (int off = 32; off > 0; off >>= 1) v += __shfl_down(v, off);
  if ((tid & 63) == 0) part[tid >> 6] = v;
  __syncthreads();
  if (tid == 0) out[0] = (float)((part[0] + part[1]) / DENOM);
}

extern "C" void kernel_launch(void* const* d_in, const int* in_sizes, int n_in,
                              void* d_out, int out_size, void* d_ws, size_t ws_size,
                              hipStream_t stream) {
  const float* pred = (const float*)d_in[0];
  const float* tgt  = (const float*)d_in[1];
  const void* a1p = d_in[2];
  const void* a2p = d_in[3];
  const void* b0p = d_in[4];
  const float* W  = (const float*)d_in[5];
  float* out = (float*)d_out;

  double* base = (double*)d_ws;
  double* wsum = base;                                   // [128] f64
  double* sbuf = base + NSLOT;                           // [30][1024][2] f64
  double* tbuf = sbuf + (size_t)NSEG * 1024 * 2;         // [30][1024][2] f64
  float2* fbuf = (float2*)(tbuf + (size_t)NSEG * 1024 * 2);  // [750][1024] f32x2
  _Float16* ybuf = (_Float16*)(fbuf + (size_t)PBLK * 1024);  // [4][40000][2][128] f16

  pass1<<<dim3(PBLK, 16), 64, 0, stream>>>(pred, tgt, a1p, a2p, b0p, fbuf, wsum);
  pass2a<<<NSEG * 16, 64, 0, stream>>>(a1p, a2p, fbuf, sbuf);
  pass2b<<<dim3(4), 256, 0, stream>>>(a1p, a2p, sbuf, tbuf);
  pass2c<<<dim3(NKV, 16), 64, 0, stream>>>(pred, tgt, a1p, a2p, b0p,
                                           fbuf, tbuf, ybuf);
  pass3<<<dim3(NKV, BATCH), 256, 0, stream>>>(W, ybuf, wsum);
  finalize<<<1, 128, 0, stream>>>(wsum, out);
}